// Round 9
// baseline (189.037 us; speedup 1.0000x reference)
//
#include <hip/hip_runtime.h>
#include <stdint.h>

#define N_PTS 65536
#define NB1 32768        // level-1 bins: score bits 31:16
#define NB2 65536        // level-2 bins: score bits 15:0 (within bin B*)
#define LCAP 2048        // LDS candidate capacity in select kernel
typedef unsigned long long u64;

// ws layout (zero region [256K, 256K+384K+64) is contiguous)
//   [0    , 256K)        scores  f32[65536]
//   [256K , 384K)        hist1   u32[32768]
//   [384K , 640K)        hist2   u32[65536]
//   [640K , 640K+64)     meta    u32 {0: done-counter}

// zero hist1+hist2+meta with uint4 stores: 98320 dwords = 24580 uint4
__global__ __launch_bounds__(256) void zero_kernel(uint4* __restrict__ z, int n4)
{
    const int i = blockIdx.x * 256 + threadIdx.x;
    const uint4 zz = {0u, 0u, 0u, 0u};
    if (i < n4) z[i] = zz;
}

// ---------------------------------------------------------------------------
// K1: MLP score (batch 0). 256 blocks x 128 threads, TWO points per thread
// (p0 = base+t, p1 = base+128+t). All weight reads wave-uniform b128
// broadcasts (conflict-free); each load feeds 8-16 FMAs (2 points).
// LDS-private histogram (R8's proven fix for the global-atomic drain).
// LDS: 128K hist + ~14K weights -> 1 block/CU, 2 waves/CU; LDS-pipe model:
// ~870 ds_read_b128/wave x 2 waves x 12cyc ~ 21K cyc ~ 8.7us/CU.
// ---------------------------------------------------------------------------
__global__ __launch_bounds__(128, 1) void score_kernel(
    const float* __restrict__ src,
    const float* __restrict__ W1, const float* __restrict__ b1,
    const float* __restrict__ W2, const float* __restrict__ b2,
    const float* __restrict__ Wa, const float* __restrict__ ba,
    const float* __restrict__ Wb, const float* __restrict__ bb,
    const float* __restrict__ Wc, const float* __restrict__ bc,
    float* __restrict__ scores, unsigned* __restrict__ hist1)
{
    __shared__ unsigned histL[NB1];                // 128 KB
    __shared__ __align__(16) float sW1[32 * 8];    // [j][0:6]=w, [6]=bias, [7]=0
    __shared__ __align__(16) float sW2[64 * 32];   // [j][i]
    __shared__ __align__(16) float sWaT[64 * 16];  // [j][q] (transposed Wa)
    __shared__ __align__(16) float sWb[8 * 16];    // [j][q]
    __shared__ float sb2[64], sba[16], sbb[8], sWc[8], sbc1[1];
    const int t = threadIdx.x;

    // zero LDS hist: 32768 dwords / 128 thr = 64 uint4 per thread
    {
        uint4* h4 = (uint4*)histL;
        const uint4 zz = {0u, 0u, 0u, 0u};
        #pragma unroll
        for (int i = 0; i < 64; i++) h4[t + 128 * i] = zz;
    }
    // stage weights
    for (int i = t; i < 256; i += 128) {
        const int j = i >> 3, c = i & 7;
        sW1[i] = (c < 6) ? W1[j * 6 + c] : ((c == 6) ? b1[j] : 0.f);
    }
    for (int i = t; i < 2048; i += 128) sW2[i] = W2[i];
    for (int i = t; i < 1024; i += 128) {
        const int j = i >> 4, q = i & 15;
        sWaT[i] = Wa[q * 64 + j];
    }
    if (t < 128) sWb[t] = Wb[t];
    if (t < 64)  sb2[t] = b2[t];
    if (t < 16)  sba[t] = ba[t];
    if (t < 8)   { sbb[t] = bb[t]; sWc[t] = Wc[t]; }
    if (t == 0)  sbc1[0] = bc[0];
    __syncthreads();

    const int base = blockIdx.x * 256;
    const int p[2] = { base + t, base + 128 + t };

    float x[2][6];
    #pragma unroll
    for (int c = 0; c < 6; c++) {
        x[0][c] = src[c * N_PTS + p[0]];
        x[1][c] = src[c * N_PTS + p[1]];
    }

    // ---- layer 1: 6 -> 32, both points ----
    float h1[2][32];
    #pragma unroll
    for (int j = 0; j < 32; j++) {
        const float4 wA = *(const float4*)&sW1[j * 8];
        const float4 wB = *(const float4*)&sW1[j * 8 + 4];   // .z = bias
        #pragma unroll
        for (int P = 0; P < 2; P++) {
            float a = wB.z;
            a = fmaf(wA.x, x[P][0], a); a = fmaf(wA.y, x[P][1], a);
            a = fmaf(wA.z, x[P][2], a); a = fmaf(wA.w, x[P][3], a);
            a = fmaf(wB.x, x[P][4], a); a = fmaf(wB.y, x[P][5], a);
            h1[P][j] = fmaxf(a, 0.f);
        }
    }

    // ---- layers 2+3 fused: 32 -> 64 -> 16, both points ----
    float h3[2][16];
    #pragma unroll
    for (int q = 0; q < 16; q++) { h3[0][q] = sba[q]; h3[1][q] = sba[q]; }

    #pragma unroll 4
    for (int j = 0; j < 64; j++) {
        const float4* w2r = (const float4*)&sW2[j * 32];
        float4 w[8];
        #pragma unroll
        for (int i = 0; i < 8; i++) w[i] = w2r[i];
        const float bj = sb2[j];
        const float4* war = (const float4*)&sWaT[j * 16];
        float4 wq[4];
        #pragma unroll
        for (int i = 0; i < 4; i++) wq[i] = war[i];
        #pragma unroll
        for (int P = 0; P < 2; P++) {
            float a0 = 0.f, a1 = 0.f, a2 = 0.f, a3 = 0.f;
            #pragma unroll
            for (int i4 = 0; i4 < 8; i4++) {
                a0 = fmaf(w[i4].x, h1[P][4 * i4 + 0], a0);
                a1 = fmaf(w[i4].y, h1[P][4 * i4 + 1], a1);
                a2 = fmaf(w[i4].z, h1[P][4 * i4 + 2], a2);
                a3 = fmaf(w[i4].w, h1[P][4 * i4 + 3], a3);
            }
            const float v = fmaxf((a0 + a1) + (a2 + a3) + bj, 0.f);
            #pragma unroll
            for (int q4 = 0; q4 < 4; q4++) {
                h3[P][4 * q4 + 0] = fmaf(wq[q4].x, v, h3[P][4 * q4 + 0]);
                h3[P][4 * q4 + 1] = fmaf(wq[q4].y, v, h3[P][4 * q4 + 1]);
                h3[P][4 * q4 + 2] = fmaf(wq[q4].z, v, h3[P][4 * q4 + 2]);
                h3[P][4 * q4 + 3] = fmaf(wq[q4].w, v, h3[P][4 * q4 + 3]);
            }
        }
    }
    #pragma unroll
    for (int q = 0; q < 16; q++) {
        h3[0][q] = fmaxf(h3[0][q], 0.f);
        h3[1][q] = fmaxf(h3[1][q], 0.f);
    }

    // ---- layers 4+5: 16 -> 8 -> 1, both points ----
    float z[2] = { sbc1[0], sbc1[0] };
    #pragma unroll
    for (int j = 0; j < 8; j++) {
        const float4* wbr = (const float4*)&sWb[j * 16];
        const float4 w0 = wbr[0], w1 = wbr[1], w2 = wbr[2], w3 = wbr[3];
        const float bj = sbb[j], wc = sWc[j];
        #pragma unroll
        for (int P = 0; P < 2; P++) {
            float s0 = bj, s1 = 0.f, s2 = 0.f, s3 = 0.f;
            s0 = fmaf(w0.x, h3[P][0],  s0); s1 = fmaf(w0.y, h3[P][1],  s1);
            s2 = fmaf(w0.z, h3[P][2],  s2); s3 = fmaf(w0.w, h3[P][3],  s3);
            s0 = fmaf(w1.x, h3[P][4],  s0); s1 = fmaf(w1.y, h3[P][5],  s1);
            s2 = fmaf(w1.z, h3[P][6],  s2); s3 = fmaf(w1.w, h3[P][7],  s3);
            s0 = fmaf(w2.x, h3[P][8],  s0); s1 = fmaf(w2.y, h3[P][9],  s1);
            s2 = fmaf(w2.z, h3[P][10], s2); s3 = fmaf(w2.w, h3[P][11], s3);
            s0 = fmaf(w3.x, h3[P][12], s0); s1 = fmaf(w3.y, h3[P][13], s1);
            s2 = fmaf(w3.z, h3[P][14], s2); s3 = fmaf(w3.w, h3[P][15], s3);
            z[P] = fmaf(wc, fmaxf((s0 + s1) + (s2 + s3), 0.f), z[P]);
        }
    }

    #pragma unroll
    for (int P = 0; P < 2; P++) {
        const float sp = fmaxf(z[P], 0.f) + log1pf(expf(-fabsf(z[P])));
        scores[p[P]] = sp;
        atomicAdd(&histL[__float_as_uint(sp) >> 16], 1u);   // LDS atomic
    }
    __syncthreads();

    // merge private hist: only nonzero bins hit global atomics
    for (int i = t; i < NB1; i += 128) {
        const unsigned v = histL[i];
        if (v) atomicAdd(&hist1[i], v);
    }
}

// ---------------------------------------------------------------------------
// K2: fused select. 64 blocks x 256 threads.
// All blocks: redundant level-1 threshold (B*, tail1) from hist1, then
// build hist2 (low-16 bits of scores in bin B*) for their 1024-pt slice.
// Last-block-done (fence + device atomic): level-2 threshold T2 -> exact
// 32-bit threshold; compact all 65536 scores into LDS (count ~ 64+ties);
// rank-select top-64 (exact lax.top_k tie order via key (bits<<32)|~idx);
// gather out[b,k,c] = src[b,c,idx[k]].
// ---------------------------------------------------------------------------
__global__ __launch_bounds__(256) void select_kernel(
    const unsigned* __restrict__ hist1, const float* __restrict__ scores,
    unsigned* __restrict__ hist2, unsigned* __restrict__ done,
    const float* __restrict__ src, float* __restrict__ out)
{
    __shared__ unsigned csum[256];
    __shared__ unsigned bsum[256];
    __shared__ u64 keys[LCAP];
    __shared__ int idxs[64];
    __shared__ int sh_c, sh_B, sh_T2, sh_cnt;
    __shared__ unsigned sh_tail, sh_rank;
    const int t = threadIdx.x;

    // ---- level-1 threshold: B* = max bin with suffix >= 64 ----
    {
        unsigned s = 0;
        const uint4* h4 = (const uint4*)(hist1 + t * 128);
        #pragma unroll
        for (int i = 0; i < 32; i++) {
            const uint4 v = h4[i];
            s += v.x + v.y + v.z + v.w;
        }
        csum[t] = s;
    }
    __syncthreads();
    for (int d = 1; d < 256; d <<= 1) {
        const unsigned v = (t + d < 256) ? csum[t + d] : 0u;
        __syncthreads();
        csum[t] += v;
        __syncthreads();
    }
    {
        const unsigned here = csum[t];
        const unsigned nxt = (t + 1 < 256) ? csum[t + 1] : 0u;
        if (here >= 64u && nxt < 64u) sh_c = t;
    }
    __syncthreads();
    const int cstar = sh_c;
    if (t < 128) bsum[t] = hist1[cstar * 128 + t];
    __syncthreads();
    {
        const unsigned ctail = (cstar + 1 < 256) ? csum[cstar + 1] : 0u;
        for (int d = 1; d < 128; d <<= 1) {
            unsigned v = 0u;
            if (t < 128 && t + d < 128) v = bsum[t + d];
            __syncthreads();
            if (t < 128) bsum[t] += v;
            __syncthreads();
        }
        if (t < 128) {
            const unsigned here = bsum[t] + ctail;
            const unsigned nxt = (t + 1 < 128) ? bsum[t + 1] + ctail : ctail;
            if (here >= 64u && nxt < 64u) { sh_B = cstar * 128 + t; sh_tail = nxt; }
        }
    }
    __syncthreads();
    const unsigned Bstar = (unsigned)sh_B;
    const unsigned tail1 = sh_tail;

    // ---- level-2 histogram over this block's 1024-score slice ----
    {
        const float4* s4 = (const float4*)scores;
        const int i = blockIdx.x * 256 + t;
        const float4 v = s4[i];
        unsigned b;
        b = __float_as_uint(v.x); if ((b >> 16) == Bstar) atomicAdd(&hist2[b & 0xFFFFu], 1u);
        b = __float_as_uint(v.y); if ((b >> 16) == Bstar) atomicAdd(&hist2[b & 0xFFFFu], 1u);
        b = __float_as_uint(v.z); if ((b >> 16) == Bstar) atomicAdd(&hist2[b & 0xFFFFu], 1u);
        b = __float_as_uint(v.w); if ((b >> 16) == Bstar) atomicAdd(&hist2[b & 0xFFFFu], 1u);
    }

    // ---- last-block-done handoff ----
    __syncthreads();
    __threadfence();
    if (t == 0) sh_rank = atomicAdd(done, 1u);
    __syncthreads();
    if (sh_rank != (unsigned)(gridDim.x - 1)) return;
    __threadfence();

    // ---- level-2 threshold: T2 = max low-bin with tail1+suffix >= 64 ----
    {
        unsigned s = 0;
        const uint4* h4 = (const uint4*)(hist2 + t * 256);
        #pragma unroll
        for (int i = 0; i < 64; i++) {
            const uint4 v = h4[i];
            s += v.x + v.y + v.z + v.w;
        }
        csum[t] = s;
    }
    __syncthreads();
    for (int d = 1; d < 256; d <<= 1) {
        const unsigned v = (t + d < 256) ? csum[t + d] : 0u;
        __syncthreads();
        csum[t] += v;
        __syncthreads();
    }
    {
        const unsigned here = tail1 + csum[t];
        const unsigned nxt = tail1 + ((t + 1 < 256) ? csum[t + 1] : 0u);
        if (here >= 64u && nxt < 64u) sh_c = t;
    }
    __syncthreads();
    const int c2 = sh_c;
    bsum[t] = hist2[c2 * 256 + t];
    __syncthreads();
    {
        const unsigned ctail = tail1 + ((c2 + 1 < 256) ? csum[c2 + 1] : 0u);
        for (int d = 1; d < 256; d <<= 1) {
            const unsigned v = (t + d < 256) ? bsum[t + d] : 0u;
            __syncthreads();
            bsum[t] += v;
            __syncthreads();
        }
        const unsigned here = bsum[t] + ctail;
        const unsigned nxt = ((t + 1 < 256) ? bsum[t + 1] : 0u) + ctail;
        if (here >= 64u && nxt < 64u) sh_T2 = c2 * 256 + t;
    }
    if (t == 0) sh_cnt = 0;
    __syncthreads();
    const unsigned T2 = (unsigned)sh_T2;

    // ---- compact: exact 32-bit threshold -> count = 64 + exact-value ties ----
    {
        const float4* s4 = (const float4*)scores;
        for (int i = t; i < N_PTS / 4; i += 256) {
            const float4 v = s4[i];
            const int n0 = 4 * i;
            unsigned b, hi;
            b = __float_as_uint(v.x); hi = b >> 16;
            if (hi > Bstar || (hi == Bstar && (b & 0xFFFFu) >= T2)) { int q = atomicAdd(&sh_cnt, 1); if (q < LCAP) keys[q] = ((u64)b << 32) | (unsigned)~(n0 + 0); }
            b = __float_as_uint(v.y); hi = b >> 16;
            if (hi > Bstar || (hi == Bstar && (b & 0xFFFFu) >= T2)) { int q = atomicAdd(&sh_cnt, 1); if (q < LCAP) keys[q] = ((u64)b << 32) | (unsigned)~(n0 + 1); }
            b = __float_as_uint(v.z); hi = b >> 16;
            if (hi > Bstar || (hi == Bstar && (b & 0xFFFFu) >= T2)) { int q = atomicAdd(&sh_cnt, 1); if (q < LCAP) keys[q] = ((u64)b << 32) | (unsigned)~(n0 + 2); }
            b = __float_as_uint(v.w); hi = b >> 16;
            if (hi > Bstar || (hi == Bstar && (b & 0xFFFFu) >= T2)) { int q = atomicAdd(&sh_cnt, 1); if (q < LCAP) keys[q] = ((u64)b << 32) | (unsigned)~(n0 + 3); }
        }
    }
    __syncthreads();

    // ---- rank-select top-64 (keys unique -> ranks are a permutation) ----
    int count = sh_cnt;
    if (count > LCAP) count = LCAP;
    for (int i = t; i < count; i += 256) {
        const u64 me = keys[i];
        int r = 0;
        for (int j = 0; j < count; j++) r += (keys[j] > me);
        if (r < 64) idxs[r] = (int)~(unsigned)(me & 0xFFFFFFFFu);
    }
    __syncthreads();

    // ---- gather: out[b, k, c] = src[b, c, idx[k]] ----
    for (int e = t; e < 3072; e += 256) {
        const int b  = e / 384;
        const int rr = e % 384;
        const int kk = rr / 6;
        const int c  = rr % 6;
        out[e] = src[(b * 6 + c) * N_PTS + idxs[kk]];
    }
}

extern "C" void kernel_launch(void* const* d_in, const int* in_sizes, int n_in,
                              void* d_out, int out_size, void* d_ws, size_t ws_size,
                              hipStream_t stream)
{
    const float* src = (const float*)d_in[0];
    const float* W1 = (const float*)d_in[2];
    const float* b1 = (const float*)d_in[3];
    const float* W2 = (const float*)d_in[4];
    const float* b2 = (const float*)d_in[5];
    const float* Wa = (const float*)d_in[6];
    const float* ba = (const float*)d_in[7];
    const float* Wb = (const float*)d_in[8];
    const float* bb = (const float*)d_in[9];
    const float* Wc = (const float*)d_in[10];
    const float* bc = (const float*)d_in[11];

    char* ws = (char*)d_ws;
    float*    scores = (float*)ws;                          // 256 KB
    unsigned* hist1  = (unsigned*)(ws + 256 * 1024);        // 128 KB
    unsigned* hist2  = (unsigned*)(ws + 384 * 1024);        // 256 KB
    unsigned* done   = (unsigned*)(ws + 640 * 1024);        // 64 B
    float*    out    = (float*)d_out;

    // zero hist1+hist2+done (contiguous, uint4): (32768+65536+16)/4 = 24580
    const int n4 = (NB1 + NB2 + 16) / 4;
    zero_kernel<<<(n4 + 255) / 256, 256, 0, stream>>>((uint4*)hist1, n4);
    score_kernel<<<256, 128, 0, stream>>>(src, W1, b1, W2, b2, Wa, ba,
                                          Wb, bb, Wc, bc, scores, hist1);
    select_kernel<<<64, 256, 0, stream>>>(hist1, scores, hist2, done, src, out);
}

// Round 10
// 136.432 us; speedup vs baseline: 1.3856x; 1.3856x over previous
//
#include <hip/hip_runtime.h>
#include <stdint.h>

#define N_PTS 65536
#define NB1 32768        // level-1 bins: score bits 31:16
#define NB2 4096         // level-2 bins: score bits 15:4 within bin B*
#define CAND_CAP 4096
#define FCAP 1024
typedef unsigned long long u64;

// ws layout (zero region [256K, 256K+144K+64) contiguous)
//   [0    , 256K)        scores  f32[65536]
//   [256K , 384K)        hist1   u32[32768]
//   [384K , 400K)        hist2   u32[4096]
//   [400K , 400K+64)     meta    i32 {0:Bstar, 1:tail1, 2:cand_count}
//   [408K , 440K)        cand    u64[4096]   (not zeroed; meta[2] counts)

__global__ __launch_bounds__(256) void zero_kernel(uint4* __restrict__ z, int n4)
{
    const int i = blockIdx.x * 256 + threadIdx.x;
    const uint4 zz = {0u, 0u, 0u, 0u};
    if (i < n4) z[i] = zz;
}

// ---------------------------------------------------------------------------
// K1: MLP score (batch 0). 128 blocks x 256 threads (4 waves/CU, 1 block/CU
// due to 128K LDS hist), TWO points per thread (p0=base+t, p1=base+256+t).
// Layer-2/3 processes NEURON PAIRS: 24 independent ds_read_b128 issued as a
// batch (the joint FMA consumption forces the register allocator to keep
// them all in flight), then 192 FMAs -> each LDS load feeds 8 FMAs.
// LDS-private histogram (R8's proven fix for the global-atomic drain).
// ---------------------------------------------------------------------------
__global__ __launch_bounds__(256, 1) void score_kernel(
    const float* __restrict__ src,
    const float* __restrict__ W1, const float* __restrict__ b1,
    const float* __restrict__ W2, const float* __restrict__ b2,
    const float* __restrict__ Wa, const float* __restrict__ ba,
    const float* __restrict__ Wb, const float* __restrict__ bb,
    const float* __restrict__ Wc, const float* __restrict__ bc,
    float* __restrict__ scores, unsigned* __restrict__ hist1)
{
    __shared__ unsigned histL[NB1];                // 128 KB
    __shared__ __align__(16) float sW1[32 * 8];    // [j][0:6]=w, [6]=bias, [7]=0
    __shared__ __align__(16) float sW2[64 * 32];   // [j][i]
    __shared__ __align__(16) float sWaT[64 * 16];  // [j][q] (transposed Wa)
    __shared__ __align__(16) float sWb[8 * 16];    // [j][q]
    __shared__ float sb2[64], sba[16], sbb[8], sWc[8], sbc1[1];
    const int t = threadIdx.x;

    // zero LDS hist: 8192 uint4 / 256 thr = 32 per thread
    {
        uint4* h4 = (uint4*)histL;
        const uint4 zz = {0u, 0u, 0u, 0u};
        #pragma unroll
        for (int i = 0; i < 32; i++) h4[t + 256 * i] = zz;
    }
    // stage weights
    {
        const int j = t >> 3, c = t & 7;
        sW1[t] = (c < 6) ? W1[j * 6 + c] : ((c == 6) ? b1[j] : 0.f);
    }
    for (int i = t; i < 2048; i += 256) sW2[i] = W2[i];
    for (int i = t; i < 1024; i += 256) {
        const int j = i >> 4, q = i & 15;
        sWaT[i] = Wa[q * 64 + j];
    }
    if (t < 128) sWb[t] = Wb[t];
    if (t < 64)  sb2[t] = b2[t];
    if (t < 16)  sba[t] = ba[t];
    if (t < 8)   { sbb[t] = bb[t]; sWc[t] = Wc[t]; }
    if (t == 0)  sbc1[0] = bc[0];
    __syncthreads();

    const int base = blockIdx.x * 512;
    const int p[2] = { base + t, base + 256 + t };

    float x[2][6];
    #pragma unroll
    for (int c = 0; c < 6; c++) {
        x[0][c] = src[c * N_PTS + p[0]];
        x[1][c] = src[c * N_PTS + p[1]];
    }

    // ---- layer 1: 6 -> 32, both points ----
    float h1[2][32];
    #pragma unroll
    for (int j = 0; j < 32; j++) {
        const float4 wA = *(const float4*)&sW1[j * 8];
        const float4 wB = *(const float4*)&sW1[j * 8 + 4];   // .z = bias
        #pragma unroll
        for (int P = 0; P < 2; P++) {
            float a = wB.z;
            a = fmaf(wA.x, x[P][0], a); a = fmaf(wA.y, x[P][1], a);
            a = fmaf(wA.z, x[P][2], a); a = fmaf(wA.w, x[P][3], a);
            a = fmaf(wB.x, x[P][4], a); a = fmaf(wB.y, x[P][5], a);
            h1[P][j] = fmaxf(a, 0.f);
        }
    }

    // ---- layers 2+3 fused: 32 -> 64 -> 16, neuron pairs, both points ----
    float h3[2][16];
    #pragma unroll
    for (int q = 0; q < 16; q++) { h3[0][q] = sba[q]; h3[1][q] = sba[q]; }

    #pragma unroll 1
    for (int jb = 0; jb < 32; jb++) {
        const int j0 = 2 * jb, j1 = j0 + 1;
        const float4* r0 = (const float4*)&sW2[j0 * 32];
        const float4* r1 = (const float4*)&sW2[j1 * 32];
        const float4* wa0 = (const float4*)&sWaT[j0 * 16];
        const float4* wa1 = (const float4*)&sWaT[j1 * 16];
        // 24 independent b128 loads, issued as one batch
        float4 u[8], v[8], q0[4], q1[4];
        #pragma unroll
        for (int i = 0; i < 8; i++) u[i] = r0[i];
        #pragma unroll
        for (int i = 0; i < 8; i++) v[i] = r1[i];
        #pragma unroll
        for (int i = 0; i < 4; i++) q0[i] = wa0[i];
        #pragma unroll
        for (int i = 0; i < 4; i++) q1[i] = wa1[i];
        const float bj0 = sb2[j0], bj1 = sb2[j1];

        #pragma unroll
        for (int P = 0; P < 2; P++) {
            float a0 = 0.f, a1 = 0.f, a2 = 0.f, a3 = 0.f;  // neuron j0
            float c0 = 0.f, c1 = 0.f, c2 = 0.f, c3 = 0.f;  // neuron j1
            #pragma unroll
            for (int i4 = 0; i4 < 8; i4++) {
                const float h0 = h1[P][4 * i4 + 0], hh1 = h1[P][4 * i4 + 1];
                const float h2 = h1[P][4 * i4 + 2], hh3 = h1[P][4 * i4 + 3];
                a0 = fmaf(u[i4].x, h0, a0); a1 = fmaf(u[i4].y, hh1, a1);
                a2 = fmaf(u[i4].z, h2, a2); a3 = fmaf(u[i4].w, hh3, a3);
                c0 = fmaf(v[i4].x, h0, c0); c1 = fmaf(v[i4].y, hh1, c1);
                c2 = fmaf(v[i4].z, h2, c2); c3 = fmaf(v[i4].w, hh3, c3);
            }
            const float v0 = fmaxf((a0 + a1) + (a2 + a3) + bj0, 0.f);
            const float v1 = fmaxf((c0 + c1) + (c2 + c3) + bj1, 0.f);
            #pragma unroll
            for (int q4 = 0; q4 < 4; q4++) {
                float t0 = h3[P][4 * q4 + 0], t1 = h3[P][4 * q4 + 1];
                float t2 = h3[P][4 * q4 + 2], t3 = h3[P][4 * q4 + 3];
                t0 = fmaf(q0[q4].x, v0, t0); t1 = fmaf(q0[q4].y, v0, t1);
                t2 = fmaf(q0[q4].z, v0, t2); t3 = fmaf(q0[q4].w, v0, t3);
                t0 = fmaf(q1[q4].x, v1, t0); t1 = fmaf(q1[q4].y, v1, t1);
                t2 = fmaf(q1[q4].z, v1, t2); t3 = fmaf(q1[q4].w, v1, t3);
                h3[P][4 * q4 + 0] = t0; h3[P][4 * q4 + 1] = t1;
                h3[P][4 * q4 + 2] = t2; h3[P][4 * q4 + 3] = t3;
            }
        }
    }
    #pragma unroll
    for (int q = 0; q < 16; q++) {
        h3[0][q] = fmaxf(h3[0][q], 0.f);
        h3[1][q] = fmaxf(h3[1][q], 0.f);
    }

    // ---- layers 4+5: 16 -> 8 -> 1, both points ----
    float z[2] = { sbc1[0], sbc1[0] };
    #pragma unroll
    for (int j = 0; j < 8; j++) {
        const float4* wbr = (const float4*)&sWb[j * 16];
        const float4 w0 = wbr[0], w1 = wbr[1], w2 = wbr[2], w3 = wbr[3];
        const float bj = sbb[j], wc = sWc[j];
        #pragma unroll
        for (int P = 0; P < 2; P++) {
            float s0 = bj, s1 = 0.f, s2 = 0.f, s3 = 0.f;
            s0 = fmaf(w0.x, h3[P][0],  s0); s1 = fmaf(w0.y, h3[P][1],  s1);
            s2 = fmaf(w0.z, h3[P][2],  s2); s3 = fmaf(w0.w, h3[P][3],  s3);
            s0 = fmaf(w1.x, h3[P][4],  s0); s1 = fmaf(w1.y, h3[P][5],  s1);
            s2 = fmaf(w1.z, h3[P][6],  s2); s3 = fmaf(w1.w, h3[P][7],  s3);
            s0 = fmaf(w2.x, h3[P][8],  s0); s1 = fmaf(w2.y, h3[P][9],  s1);
            s2 = fmaf(w2.z, h3[P][10], s2); s3 = fmaf(w2.w, h3[P][11], s3);
            s0 = fmaf(w3.x, h3[P][12], s0); s1 = fmaf(w3.y, h3[P][13], s1);
            s2 = fmaf(w3.z, h3[P][14], s2); s3 = fmaf(w3.w, h3[P][15], s3);
            z[P] = fmaf(wc, fmaxf((s0 + s1) + (s2 + s3), 0.f), z[P]);
        }
    }

    #pragma unroll
    for (int P = 0; P < 2; P++) {
        const float sp = fmaxf(z[P], 0.f) + log1pf(expf(-fabsf(z[P])));
        scores[p[P]] = sp;
        atomicAdd(&histL[__float_as_uint(sp) >> 16], 1u);   // LDS atomic
    }
    __syncthreads();

    // merge private hist: only nonzero bins hit global atomics
    for (int i = t; i < NB1; i += 256) {
        const unsigned v = histL[i];
        if (v) atomicAdd(&hist1[i], v);
    }
}

// ---------------------------------------------------------------------------
// K2: refine. 64 blocks x 256 threads, fully parallel (no last-block serial
// scan — R9's 65us mistake). Each block: redundant level-1 threshold
// (B* = max bin with suffix >= 64, tail1 = suffix(B*+1)); then over its
// 1024-score slice: compact hi >= B* into global cand (count <= 4096,
// validated R2-R7) and histogram bin-B* members into 4096 sub-bins
// (bits 15:4). Block 0 publishes {B*, tail1}.
// ---------------------------------------------------------------------------
__global__ __launch_bounds__(256) void refine_kernel(
    const unsigned* __restrict__ hist1, const float* __restrict__ scores,
    unsigned* __restrict__ hist2, int* __restrict__ meta,
    u64* __restrict__ cand)
{
    __shared__ unsigned csum[256];
    __shared__ unsigned bsum[128];
    __shared__ int sh_c, sh_B;
    __shared__ unsigned sh_tail;
    const int t = threadIdx.x;

    {
        unsigned s = 0;
        const uint4* h4 = (const uint4*)(hist1 + t * 128);
        #pragma unroll
        for (int i = 0; i < 32; i++) {
            const uint4 v = h4[i];
            s += v.x + v.y + v.z + v.w;
        }
        csum[t] = s;
    }
    __syncthreads();
    for (int d = 1; d < 256; d <<= 1) {
        const unsigned v = (t + d < 256) ? csum[t + d] : 0u;
        __syncthreads();
        csum[t] += v;
        __syncthreads();
    }
    {
        const unsigned here = csum[t];
        const unsigned nxt = (t + 1 < 256) ? csum[t + 1] : 0u;
        if (here >= 64u && nxt < 64u) sh_c = t;
    }
    __syncthreads();
    const int cstar = sh_c;
    if (t < 128) bsum[t] = hist1[cstar * 128 + t];
    __syncthreads();
    {
        const unsigned ctail = (cstar + 1 < 256) ? csum[cstar + 1] : 0u;
        for (int d = 1; d < 128; d <<= 1) {
            unsigned v = 0u;
            if (t < 128 && t + d < 128) v = bsum[t + d];
            __syncthreads();
            if (t < 128) bsum[t] += v;
            __syncthreads();
        }
        if (t < 128) {
            const unsigned here = bsum[t] + ctail;
            const unsigned nxt = (t + 1 < 128) ? bsum[t + 1] + ctail : ctail;
            if (here >= 64u && nxt < 64u) { sh_B = cstar * 128 + t; sh_tail = nxt; }
        }
    }
    __syncthreads();
    const unsigned Bstar = (unsigned)sh_B;
    if (blockIdx.x == 0 && t == 0) { meta[0] = sh_B; meta[1] = (int)sh_tail; }

    // slice pass: compact level-1 candidates + build sub-histogram
    const float4* s4 = (const float4*)scores;
    const int i = blockIdx.x * 256 + t;
    const float4 v = s4[i];
    const int n0 = 4 * i;
    #pragma unroll
    for (int k = 0; k < 4; k++) {
        const float sv = (k == 0) ? v.x : (k == 1) ? v.y : (k == 2) ? v.z : v.w;
        const unsigned b = __float_as_uint(sv);
        const unsigned hi = b >> 16;
        if (hi >= Bstar) {
            const int p = atomicAdd(&meta[2], 1);
            if (p < CAND_CAP) cand[p] = ((u64)b << 32) | (unsigned)~(n0 + k);
            if (hi == Bstar) atomicAdd(&hist2[(b & 0xFFFFu) >> 4], 1u);
        }
    }
}

// ---------------------------------------------------------------------------
// K3: final. 1 block x 256 threads, touches only small data (16KB hist2 +
// 32KB cand). Level-2 threshold T2 (sub-bin, bits 15:4) -> filter cands to
// ~64+ties -> rank-select (exact lax.top_k tie order via key
// (bits<<32)|~idx) -> gather out[b,k,c] = src[b,c,idx[k]].
// ---------------------------------------------------------------------------
__global__ __launch_bounds__(256) void final_kernel(
    const unsigned* __restrict__ hist2, const int* __restrict__ meta,
    const u64* __restrict__ cand, const float* __restrict__ src,
    float* __restrict__ out)
{
    __shared__ unsigned h2[NB2];       // 16 KB
    __shared__ unsigned csum[256];
    __shared__ u64 keys[FCAP];
    __shared__ int idxs[64];
    __shared__ int sh_c, sh_T2, sh_cnt;
    const int t = threadIdx.x;
    const unsigned Bstar = (unsigned)meta[0];
    const unsigned tail1 = (unsigned)meta[1];

    // load hist2 to LDS
    {
        uint4* d = (uint4*)h2;
        const uint4* s = (const uint4*)hist2;
        #pragma unroll
        for (int i = 0; i < 4; i++) d[t + 256 * i] = s[t + 256 * i];
    }
    __syncthreads();

    // chunk sums: 16 bins/thread
    {
        unsigned s = 0;
        #pragma unroll
        for (int i = 0; i < 16; i++) s += h2[t * 16 + i];
        csum[t] = s;
    }
    __syncthreads();
    for (int d = 1; d < 256; d <<= 1) {
        const unsigned v = (t + d < 256) ? csum[t + d] : 0u;
        __syncthreads();
        csum[t] += v;
        __syncthreads();
    }
    {
        const unsigned here = tail1 + csum[t];
        const unsigned nxt = tail1 + ((t + 1 < 256) ? csum[t + 1] : 0u);
        if (here >= 64u && nxt < 64u) sh_c = t;
    }
    __syncthreads();
    {
        const int c2 = sh_c;
        if (t == 0) {
            unsigned acc = tail1 + ((c2 + 1 < 256) ? csum[c2 + 1] : 0u);
            int T2 = c2 * 16;
            for (int b = c2 * 16 + 15; b >= c2 * 16; b--) {
                acc += h2[b];
                if (acc >= 64u) { T2 = b; break; }
            }
            sh_T2 = T2;
            sh_cnt = 0;
        }
    }
    __syncthreads();
    const unsigned T2 = (unsigned)sh_T2;

    // filter candidates: hi > B*  OR  sub-bin >= T2
    int count = meta[2];
    if (count > CAND_CAP) count = CAND_CAP;
    for (int i = t; i < count; i += 256) {
        const u64 key = cand[i];
        const unsigned b = (unsigned)(key >> 32);
        const unsigned hi = b >> 16;
        if (hi > Bstar || ((b & 0xFFFFu) >> 4) >= T2) {
            const int p = atomicAdd(&sh_cnt, 1);
            if (p < FCAP) keys[p] = key;
        }
    }
    __syncthreads();

    // rank-select top-64 (keys unique -> ranks form a permutation)
    int fcnt = sh_cnt;
    if (fcnt > FCAP) fcnt = FCAP;
    for (int i = t; i < fcnt; i += 256) {
        const u64 me = keys[i];
        int r = 0;
        for (int j = 0; j < fcnt; j++) r += (keys[j] > me);
        if (r < 64) idxs[r] = (int)~(unsigned)(me & 0xFFFFFFFFu);
    }
    __syncthreads();

    // gather: out[b, k, c] = src[b, c, idx[k]]
    for (int e = t; e < 3072; e += 256) {
        const int b  = e / 384;
        const int rr = e % 384;
        const int kk = rr / 6;
        const int c  = rr % 6;
        out[e] = src[(b * 6 + c) * N_PTS + idxs[kk]];
    }
}

extern "C" void kernel_launch(void* const* d_in, const int* in_sizes, int n_in,
                              void* d_out, int out_size, void* d_ws, size_t ws_size,
                              hipStream_t stream)
{
    const float* src = (const float*)d_in[0];
    const float* W1 = (const float*)d_in[2];
    const float* b1 = (const float*)d_in[3];
    const float* W2 = (const float*)d_in[4];
    const float* b2 = (const float*)d_in[5];
    const float* Wa = (const float*)d_in[6];
    const float* ba = (const float*)d_in[7];
    const float* Wb = (const float*)d_in[8];
    const float* bb = (const float*)d_in[9];
    const float* Wc = (const float*)d_in[10];
    const float* bc = (const float*)d_in[11];

    char* ws = (char*)d_ws;
    float*    scores = (float*)ws;                          // 256 KB
    unsigned* hist1  = (unsigned*)(ws + 256 * 1024);        // 128 KB
    unsigned* hist2  = (unsigned*)(ws + 384 * 1024);        // 16 KB
    int*      meta   = (int*)(ws + 400 * 1024);             // 64 B
    u64*      cand   = (u64*)(ws + 408 * 1024);             // 32 KB
    float*    out    = (float*)d_out;

    // zero hist1+hist2+meta (contiguous): (32768+4096+16)/4 = 9220 uint4
    const int n4 = (NB1 + NB2 + 16) / 4;
    zero_kernel<<<(n4 + 255) / 256, 256, 0, stream>>>((uint4*)hist1, n4);
    score_kernel<<<128, 256, 0, stream>>>(src, W1, b1, W2, b2, Wa, ba,
                                          Wb, bb, Wc, bc, scores, hist1);
    refine_kernel<<<64, 256, 0, stream>>>(hist1, scores, hist2, meta, cand);
    final_kernel<<<1, 256, 0, stream>>>(hist2, meta, cand, src, out);
}